// Round 14
// baseline (888.851 us; speedup 1.0000x reference)
//
#include <hip/hip_runtime.h>
#include <math.h>

// KDC Lindblad propagator — real-basis reduction + fp64 MFMA + sparse Horner.
// f64 16x16x4 C/D layout (HW-probed round 4): col=lane&15, row=(lane>>4)+4*reg.
//
// Round 14 deltas on the validated round-13 skeleton:
//  (a) dgemm: 64x32 tile, grid (16,32) = 512 blocks = 2 blocks/CU so the two
//      blocks' barriers interleave (round-13: 1 block/CU, barrier drains idle
//      the MFMA pipe -> 48.5 us vs 27.3 floor). Same wave structure as the
//      validated round-9 kernel (acc[2][2], k-split-4, 4-phase LDS reduce).
//  (b) t = a + 128j (was 64j): +1 dgemm (U^128) + 1 ydouble buys -8 zsteps.
// Pipeline: W = Taylor16(tau*T/8) [build+15 applies]; U = W^8; U^2..U^128
// (10 dgemms); Y_a (a<128) by doubling; z_j = (U^128)^j x0 (7 steps); pops.

#define DS 1024
#define MATD ((size_t)DS * DS * sizeof(double))

typedef double v4d __attribute__((ext_vector_type(4)));

__device__ inline double Qel(int i, int j) {
    if (i == j + 1) return sqrt((double)i) * 0.70710678118654752440;
    if (j == i + 1) return sqrt((double)j) * 0.70710678118654752440;
    return 0.0;
}

__device__ inline void fill_H(double* Hs, int tid) {
    const double CM2EV = 0.00012398419;
    const double E_S1 = 3.995, E_S2 = 4.9183;
    const double om6a = 596.0 * CM2EV, om10a = 919.0 * CM2EV;
    const double kapA = -0.0964, kapB = 0.1193, lam = 0.1825, gam = -0.018;
    for (int h = tid; h < 1024; h += 256) {
        int r = h >> 5, c = h & 31;
        int e = r >> 4, v6 = (r >> 2) & 3, v10 = r & 3;
        int e2 = c >> 4, w6 = (c >> 2) & 3, w10 = c & 3;
        double val = 0.0;
        if (r == c) val += (e ? E_S2 : E_S1) + om6a * v6 + om10a * v10;
        if (e == e2 && v10 == w10) val += (e ? kapB : kapA) * Qel(v6, w6);
        if (e != e2 && v6 == w6) {
            double q2 = 0.0;
            #pragma unroll
            for (int m = 0; m < 4; ++m) q2 += Qel(v10, m) * Qel(m, w10);
            val += lam * Qel(v10, w10) + gam * q2;
        }
        Hs[h] = val;
    }
}

// --------------------------------------------------------- build G16 --------
__global__ __launch_bounds__(256)
void build_G16(const float* __restrict__ logg, double* __restrict__ X)
{
    __shared__ double Hs[1024];
    int tid = threadIdx.x;
    fill_H(Hs, tid);
    __syncthreads();
    double g = exp((double)logg[0]);
    const double sc = ((1.0 / 0.6582119569) / 8.0) / 16.0;
    int idx = blockIdx.x * 256 + tid;
    int r = idx >> 10, c = idx & 1023;
    int i = r >> 5, j = r & 31;
    int k = c >> 5, l = c & 31;
    double t = 0.0;
    if (k <= l) {
        if (i <= j) {
            if (i < 16 && j < 16) {
                int p = i + 16, q = j + 16;
                if ((p == k && q == l) || (p == l && q == k)) t += g;
            }
            if (i == k && j == l) t -= 0.5 * g * ((i >= 16) + (j >= 16));
        } else {
            if (j == l) t += Hs[i * 32 + k];
            if (k != l && j == k) t += Hs[i * 32 + l];
            if (i == k) t -= Hs[l * 32 + j];
            if (k != l && i == l) t -= Hs[k * 32 + j];
        }
    } else {
        if (i <= j) {
            double ha = 0.0;
            if (j == l) ha += Hs[i * 32 + k];
            if (j == k) ha -= Hs[i * 32 + l];
            if (i == k) ha -= Hs[l * 32 + j];
            if (i == l) ha += Hs[k * 32 + j];
            t -= ha;
        } else {
            if (i < 16 && j < 16 && (i + 16 == k) && (j + 16 == l)) t += g;
            if (i == k && j == l) t -= 0.5 * g * ((i >= 16) + (j >= 16));
        }
    }
    X[idx] = t * sc + ((r == c) ? 1.0 : 0.0);
}

// --------------------------------------------------------- sparse T-apply ---
__global__ __launch_bounds__(256)
void apply_T(const float* __restrict__ logg, const double* __restrict__ M,
             double* __restrict__ O, double invk)
{
    __shared__ double Hs[1024];
    const int tid = threadIdx.x;
    fill_H(Hs, tid);
    __syncthreads();
    const double g = exp((double)logg[0]);
    const double sck = ((1.0 / 0.6582119569) / 8.0) * invk;
    const int p = blockIdx.x;
    const int i = p >> 5, j = p & 31;

    double a0 = 0.0, a1 = 0.0, a2 = 0.0, a3 = 0.0;
    const int e = tid;

#define ADDROW(q, wgt) { const double* r_ = M + (size_t)(q) * DS; double w_ = (wgt); \
    a0 += w_ * r_[e]; a1 += w_ * r_[e + 256];                                        \
    a2 += w_ * r_[e + 512]; a3 += w_ * r_[e + 768]; }

    if (i <= j) {
        for (int m = 0; m < 32; ++m) {
            double c = Hs[i * 32 + m];
            if (c != 0.0 && m != j) {
                if (m > j) ADDROW(m * 32 + j, -c)
                else       ADDROW(j * 32 + m,  c)
            }
        }
        for (int m = 0; m < 32; ++m) {
            double c = Hs[m * 32 + j];
            if (c != 0.0 && m != i) {
                if (i > m) ADDROW(i * 32 + m,  c)
                else       ADDROW(m * 32 + i, -c)
            }
        }
        if (i < 16 && j < 16) ADDROW((i + 16) * 32 + (j + 16), g)
        if (i >= 16 || j >= 16)
            ADDROW(p, -0.5 * g * (double)((i >= 16) + (j >= 16)))
    } else {
        for (int m = 0; m < 32; ++m) {
            double c = Hs[i * 32 + m];
            if (c != 0.0) {
                int lo = m < j ? m : j, hi = m < j ? j : m;
                ADDROW(lo * 32 + hi, c)
            }
        }
        for (int m = 0; m < 32; ++m) {
            double c = Hs[m * 32 + j];
            if (c != 0.0) {
                int lo = m < i ? m : i, hi = m < i ? i : m;
                ADDROW(lo * 32 + hi, -c)
            }
        }
        if (i < 16 && j < 16) ADDROW((i + 16) * 32 + (j + 16), g)
        ADDROW(p, -0.5 * g * (double)((i >= 16) + (j >= 16)))
    }
#undef ADDROW

    size_t base = (size_t)p * DS;
    O[base + e]       = sck * a0 + ((p == e)       ? 1.0 : 0.0);
    O[base + e + 256] = sck * a1 + ((p == e + 256) ? 1.0 : 0.0);
    O[base + e + 512] = sck * a2 + ((p == e + 512) ? 1.0 : 0.0);
    O[base + e + 768] = sck * a3 + ((p == e + 768) ? 1.0 : 0.0);
}

// --------------------------------------------------------- dgemm (MFMA f64) -
// D = A*B. 64x32 tile, grid (16,32) = 512 blocks = 2 blocks/CU.
// 512 threads / 8 waves: 2 output row-halves x 4 k-groups (k-split-4 in
// KT=64); 4-phase LDS k-reduction (round-9-validated pattern, halved cols).
__global__ __launch_bounds__(512, 1)
void dgemm(const double* __restrict__ A, const double* __restrict__ B,
           double* __restrict__ D)
{
    __shared__ double As[64 * 66];   // [row][k]
    __shared__ double Bs[64 * 34];   // [k][col]
    const int tid = threadIdx.x;
    const int bm = blockIdx.x << 6, bn = blockIdx.y << 5;
    const int w = tid >> 6, lane = tid & 63;
    const int lr = lane & 15, lk = lane >> 4;
    const int p = w & 1, kg = w >> 1;
    const int wr = p << 5;

    v4d acc[2][2];
    #pragma unroll
    for (int si = 0; si < 2; ++si)
        #pragma unroll
        for (int sj = 0; sj < 2; ++sj) acc[si][sj] = (v4d){0., 0., 0., 0.};

    const int ra = tid >> 3;          // 0..63
    const int cs = (tid & 7) << 3;    // A k-offset, 8 els
    const int cb = (tid & 7) << 2;    // B col-offset, 4 els
    const double* gA = A + (size_t)(bm + ra) * DS + cs;
    const double* gB = B + (size_t)ra * DS + bn + cb;
    double va[8], vb[4];
    #pragma unroll
    for (int u = 0; u < 8; ++u) va[u] = gA[u];
    #pragma unroll
    for (int u = 0; u < 4; ++u) vb[u] = gB[u];

    for (int kt = 0; kt < DS; kt += 64) {
        #pragma unroll
        for (int u = 0; u < 8; ++u) As[ra * 66 + cs + u] = va[u];
        #pragma unroll
        for (int u = 0; u < 4; ++u) Bs[ra * 34 + cb + u] = vb[u];
        __syncthreads();
        if (kt + 64 < DS) {
            #pragma unroll
            for (int u = 0; u < 8; ++u) va[u] = gA[kt + 64 + u];
            #pragma unroll
            for (int u = 0; u < 4; ++u) vb[u] = gB[(size_t)(kt + 64) * DS + u];
        }
        #pragma unroll
        for (int s = 0; s < 4; ++s) {
            int k = (kg << 4) + (s << 2) + lk;
            double a0 = As[(wr + lr) * 66 + k];
            double a1 = As[(wr + 16 + lr) * 66 + k];
            double b0 = Bs[k * 34 + lr];
            double b1 = Bs[k * 34 + 16 + lr];
            acc[0][0] = __builtin_amdgcn_mfma_f64_16x16x4f64(a0, b0, acc[0][0], 0, 0, 0);
            acc[0][1] = __builtin_amdgcn_mfma_f64_16x16x4f64(a0, b1, acc[0][1], 0, 0, 0);
            acc[1][0] = __builtin_amdgcn_mfma_f64_16x16x4f64(a1, b0, acc[1][0], 0, 0, 0);
            acc[1][1] = __builtin_amdgcn_mfma_f64_16x16x4f64(a1, b1, acc[1][1], 0, 0, 0);
        }
        __syncthreads();
    }

    // 4-phase k-reduction; red = 64x32 in As space. p-halves are disjoint.
    double* red = As;
    if (kg == 3) {
        #pragma unroll
        for (int si = 0; si < 2; ++si)
            #pragma unroll
            for (int sj = 0; sj < 2; ++sj)
                #pragma unroll
                for (int r = 0; r < 4; ++r)
                    red[(wr + si * 16 + lk + 4 * r) * 32 + sj * 16 + lr]
                        = acc[si][sj][r];
    }
    __syncthreads();
    if (kg == 2) {
        #pragma unroll
        for (int si = 0; si < 2; ++si)
            #pragma unroll
            for (int sj = 0; sj < 2; ++sj)
                #pragma unroll
                for (int r = 0; r < 4; ++r)
                    red[(wr + si * 16 + lk + 4 * r) * 32 + sj * 16 + lr]
                        += acc[si][sj][r];
    }
    __syncthreads();
    if (kg == 1) {
        #pragma unroll
        for (int si = 0; si < 2; ++si)
            #pragma unroll
            for (int sj = 0; sj < 2; ++sj)
                #pragma unroll
                for (int r = 0; r < 4; ++r)
                    red[(wr + si * 16 + lk + 4 * r) * 32 + sj * 16 + lr]
                        += acc[si][sj][r];
    }
    __syncthreads();
    if (kg == 0) {
        #pragma unroll
        for (int si = 0; si < 2; ++si)
            #pragma unroll
            for (int sj = 0; sj < 2; ++sj) {
                int col = bn + sj * 16 + lr;
                #pragma unroll
                for (int r = 0; r < 4; ++r) {
                    int row = bm + wr + si * 16 + lk + 4 * r;
                    D[(size_t)row * DS + col] = acc[si][sj][r]
                        + red[(wr + si * 16 + lk + 4 * r) * 32 + sj * 16 + lr];
                }
            }
    }
}

// --------------------------------------------------------- init Y/Z ---------
// Y: 256 rows (r = 2a+k, a<128). Rows 0,1 = trace rows; rest zero.
__global__ __launch_bounds__(256)
void init_YZ(double* __restrict__ Y, double* __restrict__ Z)
{
    int idx = blockIdx.x * 256 + threadIdx.x;
    if (idx < 256 * 1024) {
        int r = idx >> 10, i = idx & 1023;
        double v = 0.0;
        if (r < 2 && i % 33 == 0) {
            int a = i / 33;
            if ((a < 16) == (r == 0)) v = 1.0;
        }
        Y[idx] = v;
    } else if (idx < 256 * 1024 + 1024) {
        int i = idx - 256 * 1024;
        Z[i] = (i == 528) ? 1.0 : 0.0;
    }
}

// --------------------------------------------------------- ypart ------------
__global__ __launch_bounds__(256)
void ypart(const double* __restrict__ P, const double* __restrict__ Y,
           double* __restrict__ scratch, int SR)
{
    __shared__ double Yld[32 * 64];
    __shared__ double red[32 * 64];
    const int tid = threadIdx.x;
    const int cc = tid & 63, kw = tid >> 6;
    const int col = (blockIdx.x << 6) + cc;
    const int kb = blockIdx.y << 6;
    const int r0 = blockIdx.z << 5;

    for (int idx = tid; idx < 32 * 64; idx += 256) {
        int r = idx >> 6, kk = idx & 63;
        Yld[idx] = Y[(size_t)(r0 + r) * DS + kb + kk];
    }
    __syncthreads();

    double acc[32];
    #pragma unroll
    for (int r = 0; r < 32; ++r) acc[r] = 0.0;

    #pragma unroll
    for (int kk = 0; kk < 16; ++kk) {
        int kl = (kw << 4) + kk;
        double pv = P[(size_t)(kb + kl) * DS + col];
        #pragma unroll
        for (int r = 0; r < 32; ++r)
            acc[r] += Yld[(r << 6) + kl] * pv;
    }

    __syncthreads();
    if (kw == 3) {
        #pragma unroll
        for (int r = 0; r < 32; ++r) red[(r << 6) + cc] = acc[r];
    }
    __syncthreads();
    if (kw == 2) {
        #pragma unroll
        for (int r = 0; r < 32; ++r) red[(r << 6) + cc] += acc[r];
    }
    __syncthreads();
    if (kw == 1) {
        #pragma unroll
        for (int r = 0; r < 32; ++r) red[(r << 6) + cc] += acc[r];
    }
    __syncthreads();
    if (kw == 0) {
        #pragma unroll
        for (int r = 0; r < 32; ++r) red[(r << 6) + cc] += acc[r];
    }
    __syncthreads();
    for (int idx = tid; idx < 32 * 64; idx += 256) {
        int r = idx >> 6, c2 = idx & 63;
        scratch[((size_t)blockIdx.y * SR + r0 + r) * DS + (blockIdx.x << 6) + c2]
            = red[idx];
    }
}

// --------------------------------------------------------- yreduce ----------
__global__ __launch_bounds__(256)
void yreduce(const double* __restrict__ scratch, double* __restrict__ Y,
             int M, int SR)
{
    int idx = blockIdx.x * 256 + threadIdx.x;
    int r = idx >> 10, c = idx & 1023;
    double s = 0.0;
    #pragma unroll
    for (int q = 0; q < 16; ++q)
        s += scratch[((size_t)q * SR + r) * DS + c];
    Y[(size_t)(M + r) * DS + c] = s;
}

// --------------------------------------------------------- Z matvec ---------
__global__ __launch_bounds__(256)
void zstep(const double* __restrict__ V, const double* __restrict__ Zin,
           double* __restrict__ Zout)
{
    int row = blockIdx.x * 4 + (threadIdx.x >> 6);
    int lane = threadIdx.x & 63;
    const double* r_ = V + (size_t)row * DS;
    double s = 0.0;
    for (int k = lane; k < DS; k += 64) s += r_[k] * Zin[k];
    #pragma unroll
    for (int off = 32; off; off >>= 1) s += __shfl_down(s, off);
    if (lane == 0) Zout[row] = s;
}

// --------------------------------------------------------- output -----------
// t = a + 128 j; y = Y row (2a+k); z = Z[j].
__global__ __launch_bounds__(128)
void final_pops(const double* __restrict__ Y, const double* __restrict__ Z,
                float* __restrict__ out, int n)
{
    int t = blockIdx.x;
    int k = threadIdx.x >> 6, lane = threadIdx.x & 63;
    int a = t & 127, j = t >> 7;
    const double* y = Y + (size_t)(2 * a + k) * 1024;
    const double* z = Z + (size_t)j * 1024;
    double s = 0.0;
    for (int i = lane; i < 1024; i += 64) s += y[i] * z[i];
    #pragma unroll
    for (int off = 32; off; off >>= 1) s += __shfl_down(s, off);
    if (lane == 0) {
        out[(size_t)(k + 1) * n + t] = (float)s;
        if (k == 0) out[t] = 0.0f;
    }
}

// --------------------------------------------------------- host -------------
static inline void ydouble2(const double* P, double* Y, double* scr, int M,
                            hipStream_t stream)
{
    int gz = (M + 31) / 32; if (gz < 1) gz = 1;
    int SR = gz * 32;
    ypart<<<dim3(16, 16, gz), 256, 0, stream>>>(P, Y, scr, SR);
    yreduce<<<SR * 4, 256, 0, stream>>>(scr, Y, M, SR);
}

extern "C" void kernel_launch(void* const* d_in, const int* in_sizes, int n_in,
                              void* d_out, int out_size, void* d_ws, size_t ws_size,
                              hipStream_t stream)
{
    const float* logg = (const float*)d_in[0];
    float* out = (float*)d_out;
    const int n = out_size / 3;
    (void)in_sizes; (void)n_in; (void)ws_size;

    char* ws = (char*)d_ws;
    double* b0 = (double*)(ws + 0 * MATD);
    double* b1 = (double*)(ws + 1 * MATD);
    double* b2 = (double*)(ws + 2 * MATD);
    double* scr = (double*)(ws + 3 * MATD);  // up to 16 x 128 x 1024 (16 MB)
    double* Y  = (double*)(ws + 5 * MATD);   // 256 rows x 1024 (2 MB)
    double* Z  = Y + 256 * 1024;             // 8 x 1024

    dim3 gg(16, 32);

    // ---- W = Taylor16(tau*T/8): G16 dense, then 15 sparse applies ----
    build_G16<<<4096, 256, 0, stream>>>(logg, b0);
    double* src = b0; double* dst = b1;
    for (int k = 15; k >= 1; --k) {
        apply_T<<<1024, 256, 0, stream>>>(logg, src, dst, 1.0 / (double)k);
        double* t = src; src = dst; dst = t;
    }
    // W in b1

    init_YZ<<<1028, 256, 0, stream>>>(Y, Z);

    // ---- squarings interleaved with Y-doubling ----
    dgemm<<<gg, 512, 0, stream>>>(b1, b1, b0);    // W^2
    dgemm<<<gg, 512, 0, stream>>>(b0, b0, b2);    // W^4
    dgemm<<<gg, 512, 0, stream>>>(b2, b2, b0);    // U = W^8
    ydouble2(b0, Y, scr, 2, stream);              // a += 1   (U)
    dgemm<<<gg, 512, 0, stream>>>(b0, b0, b1);    // U^2
    ydouble2(b1, Y, scr, 4, stream);              // a += 2
    dgemm<<<gg, 512, 0, stream>>>(b1, b1, b2);    // U^4
    ydouble2(b2, Y, scr, 8, stream);              // a += 4
    dgemm<<<gg, 512, 0, stream>>>(b2, b2, b1);    // U^8
    ydouble2(b1, Y, scr, 16, stream);             // a += 8
    dgemm<<<gg, 512, 0, stream>>>(b1, b1, b2);    // U^16
    ydouble2(b2, Y, scr, 32, stream);             // a += 16
    dgemm<<<gg, 512, 0, stream>>>(b2, b2, b1);    // U^32
    ydouble2(b1, Y, scr, 64, stream);             // a += 32
    dgemm<<<gg, 512, 0, stream>>>(b1, b1, b2);    // U^64
    ydouble2(b2, Y, scr, 128, stream);            // a += 64
    dgemm<<<gg, 512, 0, stream>>>(b2, b2, b1);    // U^128

    // ---- Z chain: z_j = (U^128)^j x0, j = 1..7 ----
    for (int j = 1; j < 8; ++j)
        zstep<<<256, 256, 0, stream>>>(b1, Z + (size_t)(j - 1) * 1024,
                                       Z + (size_t)j * 1024);

    final_pops<<<n, 128, 0, stream>>>(Y, Z, out, n);
}

// Round 15
// 830.609 us; speedup vs baseline: 1.0701x; 1.0701x over previous
//
#include <hip/hip_runtime.h>
#include <math.h>

// KDC Lindblad propagator — real-basis reduction + fp64 MFMA + sparse Horner.
// f64 16x16x4 C/D layout (HW-probed round 4): col=lane&15, row=(lane>>4)+4*reg.
//
// Round 15 = consolidation:
//  - dgemm: round-9 config FROZEN (grid 16x16, 1024 thr, PA=66; 48.5 us
//    measured). Four variants (512-thr, k-split-2, 64x32 tile) all regressed:
//    94/107/54 us. Remaining gap to the 27.3 us MFMA floor needs an
//    interleaved-vmcnt K-loop rewrite — negative EV here.
//  - t = a + 128j rebalance kept (validated round 14): 10 dgemms, 7 zsteps.
//  - zstep: double2 loads (16 B/lane); init_YZ folded into build_G16.
// Pipeline: W = Taylor16(tau*T/8) [build+15 applies]; U = W^8; U^2..U^128;
// Y_a (a<128) by doubling off chain intermediates; z_j = (U^128)^j x0; pops.

#define DS 1024
#define MATD ((size_t)DS * DS * sizeof(double))
#define PA 66

typedef double v4d __attribute__((ext_vector_type(4)));

__device__ inline double Qel(int i, int j) {
    if (i == j + 1) return sqrt((double)i) * 0.70710678118654752440;
    if (j == i + 1) return sqrt((double)j) * 0.70710678118654752440;
    return 0.0;
}

__device__ inline void fill_H(double* Hs, int tid) {
    const double CM2EV = 0.00012398419;
    const double E_S1 = 3.995, E_S2 = 4.9183;
    const double om6a = 596.0 * CM2EV, om10a = 919.0 * CM2EV;
    const double kapA = -0.0964, kapB = 0.1193, lam = 0.1825, gam = -0.018;
    for (int h = tid; h < 1024; h += 256) {
        int r = h >> 5, c = h & 31;
        int e = r >> 4, v6 = (r >> 2) & 3, v10 = r & 3;
        int e2 = c >> 4, w6 = (c >> 2) & 3, w10 = c & 3;
        double val = 0.0;
        if (r == c) val += (e ? E_S2 : E_S1) + om6a * v6 + om10a * v10;
        if (e == e2 && v10 == w10) val += (e ? kapB : kapA) * Qel(v6, w6);
        if (e != e2 && v6 == w6) {
            double q2 = 0.0;
            #pragma unroll
            for (int m = 0; m < 4; ++m) q2 += Qel(v10, m) * Qel(m, w10);
            val += lam * Qel(v10, w10) + gam * q2;
        }
        Hs[h] = val;
    }
}

// ------------------------------------------------ build G16 (+ Y/Z init) ----
// Blocks < 4096: G = I + sc*T. Blocks >= 4096: init Y (256 rows) and Z.
__global__ __launch_bounds__(256)
void build_G16(const float* __restrict__ logg, double* __restrict__ X,
               double* __restrict__ Y, double* __restrict__ Z)
{
    int tid = threadIdx.x;
    if (blockIdx.x >= 4096) {
        int idx = (blockIdx.x - 4096) * 256 + tid;
        if (idx < 256 * 1024) {
            int r = idx >> 10, i = idx & 1023;
            double v = 0.0;
            if (r < 2 && i % 33 == 0) {
                int a = i / 33;
                if ((a < 16) == (r == 0)) v = 1.0;
            }
            Y[idx] = v;
        } else if (idx < 256 * 1024 + 1024) {
            int i = idx - 256 * 1024;
            Z[i] = (i == 528) ? 1.0 : 0.0;
        }
        return;
    }
    __shared__ double Hs[1024];
    fill_H(Hs, tid);
    __syncthreads();
    double g = exp((double)logg[0]);
    const double sc = ((1.0 / 0.6582119569) / 8.0) / 16.0;
    int idx = blockIdx.x * 256 + tid;
    int r = idx >> 10, c = idx & 1023;
    int i = r >> 5, j = r & 31;
    int k = c >> 5, l = c & 31;
    double t = 0.0;
    if (k <= l) {
        if (i <= j) {
            if (i < 16 && j < 16) {
                int p = i + 16, q = j + 16;
                if ((p == k && q == l) || (p == l && q == k)) t += g;
            }
            if (i == k && j == l) t -= 0.5 * g * ((i >= 16) + (j >= 16));
        } else {
            if (j == l) t += Hs[i * 32 + k];
            if (k != l && j == k) t += Hs[i * 32 + l];
            if (i == k) t -= Hs[l * 32 + j];
            if (k != l && i == l) t -= Hs[k * 32 + j];
        }
    } else {
        if (i <= j) {
            double ha = 0.0;
            if (j == l) ha += Hs[i * 32 + k];
            if (j == k) ha -= Hs[i * 32 + l];
            if (i == k) ha -= Hs[l * 32 + j];
            if (i == l) ha += Hs[k * 32 + j];
            t -= ha;
        } else {
            if (i < 16 && j < 16 && (i + 16 == k) && (j + 16 == l)) t += g;
            if (i == k && j == l) t -= 0.5 * g * ((i >= 16) + (j >= 16));
        }
    }
    X[idx] = t * sc + ((r == c) ? 1.0 : 0.0);
}

// --------------------------------------------------------- sparse T-apply ---
__global__ __launch_bounds__(256)
void apply_T(const float* __restrict__ logg, const double* __restrict__ M,
             double* __restrict__ O, double invk)
{
    __shared__ double Hs[1024];
    const int tid = threadIdx.x;
    fill_H(Hs, tid);
    __syncthreads();
    const double g = exp((double)logg[0]);
    const double sck = ((1.0 / 0.6582119569) / 8.0) * invk;
    const int p = blockIdx.x;
    const int i = p >> 5, j = p & 31;

    double a0 = 0.0, a1 = 0.0, a2 = 0.0, a3 = 0.0;
    const int e = tid;

#define ADDROW(q, wgt) { const double* r_ = M + (size_t)(q) * DS; double w_ = (wgt); \
    a0 += w_ * r_[e]; a1 += w_ * r_[e + 256];                                        \
    a2 += w_ * r_[e + 512]; a3 += w_ * r_[e + 768]; }

    if (i <= j) {
        for (int m = 0; m < 32; ++m) {
            double c = Hs[i * 32 + m];
            if (c != 0.0 && m != j) {
                if (m > j) ADDROW(m * 32 + j, -c)
                else       ADDROW(j * 32 + m,  c)
            }
        }
        for (int m = 0; m < 32; ++m) {
            double c = Hs[m * 32 + j];
            if (c != 0.0 && m != i) {
                if (i > m) ADDROW(i * 32 + m,  c)
                else       ADDROW(m * 32 + i, -c)
            }
        }
        if (i < 16 && j < 16) ADDROW((i + 16) * 32 + (j + 16), g)
        if (i >= 16 || j >= 16)
            ADDROW(p, -0.5 * g * (double)((i >= 16) + (j >= 16)))
    } else {
        for (int m = 0; m < 32; ++m) {
            double c = Hs[i * 32 + m];
            if (c != 0.0) {
                int lo = m < j ? m : j, hi = m < j ? j : m;
                ADDROW(lo * 32 + hi, c)
            }
        }
        for (int m = 0; m < 32; ++m) {
            double c = Hs[m * 32 + j];
            if (c != 0.0) {
                int lo = m < i ? m : i, hi = m < i ? i : m;
                ADDROW(lo * 32 + hi, -c)
            }
        }
        if (i < 16 && j < 16) ADDROW((i + 16) * 32 + (j + 16), g)
        ADDROW(p, -0.5 * g * (double)((i >= 16) + (j >= 16)))
    }
#undef ADDROW

    size_t base = (size_t)p * DS;
    O[base + e]       = sck * a0 + ((p == e)       ? 1.0 : 0.0);
    O[base + e + 256] = sck * a1 + ((p == e + 256) ? 1.0 : 0.0);
    O[base + e + 512] = sck * a2 + ((p == e + 512) ? 1.0 : 0.0);
    O[base + e + 768] = sck * a3 + ((p == e + 768) ? 1.0 : 0.0);
}

// --------------------------------------------------------- dgemm (MFMA f64) -
// ROUND-9 VERBATIM (FROZEN). D = A*B. 64x64 tile, 1024 threads (16 waves):
// 4 output quadrants x 4 k-groups (k-split-4 within KT=64); 3-phase reduction.
__global__ __launch_bounds__(1024, 1)
void dgemm(const double* __restrict__ A, const double* __restrict__ B,
           double* __restrict__ D)
{
    __shared__ double As[64 * PA];
    __shared__ double Bs[64 * PA];
    const int tid = threadIdx.x;
    const int bm = blockIdx.x << 6, bn = blockIdx.y << 6;
    const int w = tid >> 6, lane = tid & 63;
    const int lr = lane & 15, lk = lane >> 4;
    const int p = w & 3, kg = w >> 2;
    const int wr = (p >> 1) << 5, wc = (p & 1) << 5;

    v4d acc[2][2];
    #pragma unroll
    for (int si = 0; si < 2; ++si)
        #pragma unroll
        for (int sj = 0; sj < 2; ++sj) acc[si][sj] = (v4d){0., 0., 0., 0.};

    const int ra = tid >> 4;
    const int cs = (tid & 15) << 2;
    const double* gA = A + (size_t)(bm + ra) * DS + cs;
    const double* gB = B + (size_t)ra * DS + bn + cs;
    double va[4], vb[4];
    #pragma unroll
    for (int u = 0; u < 4; ++u) { va[u] = gA[u]; vb[u] = gB[u]; }

    for (int kt = 0; kt < DS; kt += 64) {
        #pragma unroll
        for (int u = 0; u < 4; ++u) {
            As[ra * PA + cs + u] = va[u];
            Bs[ra * PA + cs + u] = vb[u];
        }
        __syncthreads();
        if (kt + 64 < DS) {
            #pragma unroll
            for (int u = 0; u < 4; ++u) {
                va[u] = gA[kt + 64 + u];
                vb[u] = gB[(size_t)(kt + 64) * DS + u];
            }
        }
        #pragma unroll
        for (int s = 0; s < 4; ++s) {
            int k = (kg << 4) + (s << 2) + lk;
            double a0 = As[(wr + lr) * PA + k];
            double a1 = As[(wr + 16 + lr) * PA + k];
            double b0 = Bs[k * PA + wc + lr];
            double b1 = Bs[k * PA + wc + 16 + lr];
            acc[0][0] = __builtin_amdgcn_mfma_f64_16x16x4f64(a0, b0, acc[0][0], 0, 0, 0);
            acc[0][1] = __builtin_amdgcn_mfma_f64_16x16x4f64(a0, b1, acc[0][1], 0, 0, 0);
            acc[1][0] = __builtin_amdgcn_mfma_f64_16x16x4f64(a1, b0, acc[1][0], 0, 0, 0);
            acc[1][1] = __builtin_amdgcn_mfma_f64_16x16x4f64(a1, b1, acc[1][1], 0, 0, 0);
        }
        __syncthreads();
    }

    double* red = As;
    if (kg == 3) {
        #pragma unroll
        for (int si = 0; si < 2; ++si)
            #pragma unroll
            for (int sj = 0; sj < 2; ++sj)
                #pragma unroll
                for (int r = 0; r < 4; ++r)
                    red[(wr + si * 16 + lk + 4 * r) * 64 + wc + sj * 16 + lr]
                        = acc[si][sj][r];
    }
    __syncthreads();
    if (kg == 2) {
        #pragma unroll
        for (int si = 0; si < 2; ++si)
            #pragma unroll
            for (int sj = 0; sj < 2; ++sj)
                #pragma unroll
                for (int r = 0; r < 4; ++r)
                    red[(wr + si * 16 + lk + 4 * r) * 64 + wc + sj * 16 + lr]
                        += acc[si][sj][r];
    }
    __syncthreads();
    if (kg == 1) {
        #pragma unroll
        for (int si = 0; si < 2; ++si)
            #pragma unroll
            for (int sj = 0; sj < 2; ++sj)
                #pragma unroll
                for (int r = 0; r < 4; ++r)
                    red[(wr + si * 16 + lk + 4 * r) * 64 + wc + sj * 16 + lr]
                        += acc[si][sj][r];
    }
    __syncthreads();
    if (kg == 0) {
        #pragma unroll
        for (int si = 0; si < 2; ++si)
            #pragma unroll
            for (int sj = 0; sj < 2; ++sj) {
                int col = bn + wc + sj * 16 + lr;
                #pragma unroll
                for (int r = 0; r < 4; ++r) {
                    int row = bm + wr + si * 16 + lk + 4 * r;
                    D[(size_t)row * DS + col] = acc[si][sj][r]
                        + red[(wr + si * 16 + lk + 4 * r) * 64 + wc + sj * 16 + lr];
                }
            }
    }
}

// --------------------------------------------------------- ypart ------------
__global__ __launch_bounds__(256)
void ypart(const double* __restrict__ P, const double* __restrict__ Y,
           double* __restrict__ scratch, int SR)
{
    __shared__ double Yld[32 * 64];
    __shared__ double red[32 * 64];
    const int tid = threadIdx.x;
    const int cc = tid & 63, kw = tid >> 6;
    const int col = (blockIdx.x << 6) + cc;
    const int kb = blockIdx.y << 6;
    const int r0 = blockIdx.z << 5;

    for (int idx = tid; idx < 32 * 64; idx += 256) {
        int r = idx >> 6, kk = idx & 63;
        Yld[idx] = Y[(size_t)(r0 + r) * DS + kb + kk];
    }
    __syncthreads();

    double acc[32];
    #pragma unroll
    for (int r = 0; r < 32; ++r) acc[r] = 0.0;

    #pragma unroll
    for (int kk = 0; kk < 16; ++kk) {
        int kl = (kw << 4) + kk;
        double pv = P[(size_t)(kb + kl) * DS + col];
        #pragma unroll
        for (int r = 0; r < 32; ++r)
            acc[r] += Yld[(r << 6) + kl] * pv;
    }

    __syncthreads();
    if (kw == 3) {
        #pragma unroll
        for (int r = 0; r < 32; ++r) red[(r << 6) + cc] = acc[r];
    }
    __syncthreads();
    if (kw == 2) {
        #pragma unroll
        for (int r = 0; r < 32; ++r) red[(r << 6) + cc] += acc[r];
    }
    __syncthreads();
    if (kw == 1) {
        #pragma unroll
        for (int r = 0; r < 32; ++r) red[(r << 6) + cc] += acc[r];
    }
    __syncthreads();
    if (kw == 0) {
        #pragma unroll
        for (int r = 0; r < 32; ++r) red[(r << 6) + cc] += acc[r];
    }
    __syncthreads();
    for (int idx = tid; idx < 32 * 64; idx += 256) {
        int r = idx >> 6, c2 = idx & 63;
        scratch[((size_t)blockIdx.y * SR + r0 + r) * DS + (blockIdx.x << 6) + c2]
            = red[idx];
    }
}

// --------------------------------------------------------- yreduce ----------
__global__ __launch_bounds__(256)
void yreduce(const double* __restrict__ scratch, double* __restrict__ Y,
             int M, int SR)
{
    int idx = blockIdx.x * 256 + threadIdx.x;
    int r = idx >> 10, c = idx & 1023;
    double s = 0.0;
    #pragma unroll
    for (int q = 0; q < 16; ++q)
        s += scratch[((size_t)q * SR + r) * DS + c];
    Y[(size_t)(M + r) * DS + c] = s;
}

// --------------------------------------------------------- Z matvec ---------
// double2 loads: 8 coalesced 16 B/lane iterations per row.
__global__ __launch_bounds__(256)
void zstep(const double* __restrict__ V, const double* __restrict__ Zin,
           double* __restrict__ Zout)
{
    int row = blockIdx.x * 4 + (threadIdx.x >> 6);
    int lane = threadIdx.x & 63;
    const double2* r_ = (const double2*)(V + (size_t)row * DS);
    const double2* z_ = (const double2*)Zin;
    double s = 0.0;
    #pragma unroll
    for (int k = 0; k < 8; ++k) {
        double2 a = r_[(k << 6) + lane];
        double2 b = z_[(k << 6) + lane];
        s += a.x * b.x + a.y * b.y;
    }
    #pragma unroll
    for (int off = 32; off; off >>= 1) s += __shfl_down(s, off);
    if (lane == 0) Zout[row] = s;
}

// --------------------------------------------------------- output -----------
// t = a + 128 j; y = Y row (2a+k); z = Z[j].
__global__ __launch_bounds__(128)
void final_pops(const double* __restrict__ Y, const double* __restrict__ Z,
                float* __restrict__ out, int n)
{
    int t = blockIdx.x;
    int k = threadIdx.x >> 6, lane = threadIdx.x & 63;
    int a = t & 127, j = t >> 7;
    const double* y = Y + (size_t)(2 * a + k) * 1024;
    const double* z = Z + (size_t)j * 1024;
    double s = 0.0;
    for (int i = lane; i < 1024; i += 64) s += y[i] * z[i];
    #pragma unroll
    for (int off = 32; off; off >>= 1) s += __shfl_down(s, off);
    if (lane == 0) {
        out[(size_t)(k + 1) * n + t] = (float)s;
        if (k == 0) out[t] = 0.0f;
    }
}

// --------------------------------------------------------- host -------------
static inline void ydouble2(const double* P, double* Y, double* scr, int M,
                            hipStream_t stream)
{
    int gz = (M + 31) / 32; if (gz < 1) gz = 1;
    int SR = gz * 32;
    ypart<<<dim3(16, 16, gz), 256, 0, stream>>>(P, Y, scr, SR);
    yreduce<<<SR * 4, 256, 0, stream>>>(scr, Y, M, SR);
}

extern "C" void kernel_launch(void* const* d_in, const int* in_sizes, int n_in,
                              void* d_out, int out_size, void* d_ws, size_t ws_size,
                              hipStream_t stream)
{
    const float* logg = (const float*)d_in[0];
    float* out = (float*)d_out;
    const int n = out_size / 3;
    (void)in_sizes; (void)n_in; (void)ws_size;

    char* ws = (char*)d_ws;
    double* b0 = (double*)(ws + 0 * MATD);
    double* b1 = (double*)(ws + 1 * MATD);
    double* b2 = (double*)(ws + 2 * MATD);
    double* scr = (double*)(ws + 3 * MATD);  // up to 16 x 128 x 1024 (16 MB)
    double* Y  = (double*)(ws + 5 * MATD);   // 256 rows x 1024 (2 MB)
    double* Z  = Y + 256 * 1024;             // 8 x 1024

    dim3 g2(16, 16);

    // ---- W = Taylor16(tau*T/8): G16 dense (+Y/Z init), 15 sparse applies ---
    build_G16<<<4096 + 1028, 256, 0, stream>>>(logg, b0, Y, Z);
    double* src = b0; double* dst = b1;
    for (int k = 15; k >= 1; --k) {
        apply_T<<<1024, 256, 0, stream>>>(logg, src, dst, 1.0 / (double)k);
        double* t = src; src = dst; dst = t;
    }
    // W in b1

    // ---- squarings interleaved with Y-doubling ----
    dgemm<<<g2, 1024, 0, stream>>>(b1, b1, b0);   // W^2
    dgemm<<<g2, 1024, 0, stream>>>(b0, b0, b2);   // W^4
    dgemm<<<g2, 1024, 0, stream>>>(b2, b2, b0);   // U = W^8
    ydouble2(b0, Y, scr, 2, stream);              // a += 1   (U)
    dgemm<<<g2, 1024, 0, stream>>>(b0, b0, b1);   // U^2
    ydouble2(b1, Y, scr, 4, stream);              // a += 2
    dgemm<<<g2, 1024, 0, stream>>>(b1, b1, b2);   // U^4
    ydouble2(b2, Y, scr, 8, stream);              // a += 4
    dgemm<<<g2, 1024, 0, stream>>>(b2, b2, b1);   // U^8
    ydouble2(b1, Y, scr, 16, stream);             // a += 8
    dgemm<<<g2, 1024, 0, stream>>>(b1, b1, b2);   // U^16
    ydouble2(b2, Y, scr, 32, stream);             // a += 16
    dgemm<<<g2, 1024, 0, stream>>>(b2, b2, b1);   // U^32
    ydouble2(b1, Y, scr, 64, stream);             // a += 32
    dgemm<<<g2, 1024, 0, stream>>>(b1, b1, b2);   // U^64
    ydouble2(b2, Y, scr, 128, stream);            // a += 64
    dgemm<<<g2, 1024, 0, stream>>>(b2, b2, b1);   // U^128

    // ---- Z chain: z_j = (U^128)^j x0, j = 1..7 ----
    for (int j = 1; j < 8; ++j)
        zstep<<<256, 256, 0, stream>>>(b1, Z + (size_t)(j - 1) * 1024,
                                       Z + (size_t)j * 1024);

    final_pops<<<n, 128, 0, stream>>>(Y, Z, out, n);
}

// Round 16
// 784.307 us; speedup vs baseline: 1.1333x; 1.0590x over previous
//
#include <hip/hip_runtime.h>
#include <math.h>

// KDC Lindblad propagator — real-basis reduction + fp64 MFMA + sparse Horner.
// f64 16x16x4 C/D layout (HW-probed round 4): col=lane&15, row=(lane>>4)+4*reg.
//
// Round 16 deltas on the validated round-15 skeleton (830 us):
//  (a) apply_T: XCD chunk-swizzle p = (bx&7)*128 + (bx>>3) — row q's ~14
//      consumer blocks (p±1,2,±32,64,±528) were spread over ~6 XCDs ->
//      ~6x L2 replication -> L3 spill (measured ~11 TB/s). Chunking keeps
//      consumers on one XCD -> ~2 MB/XCD, L2-resident.
//  (b) Taylor m 16 -> 14 (trunc 4e-7, x1024 squaring amplification ~2e-3
//      worst case vs 2e-2 threshold): build is the k=14 Horner step, 13
//      applies (was 15).
//  dgemm FROZEN (round-9 config, 48.3 us; 4 variants all regressed).
// Pipeline: W = Taylor14(tau*T/8); U = W^8; U^2..U^128 (10 dgemms) with
// Y-doubling off chain intermediates (t = a + 128j); z_j = (U^128)^j x0; pops.

#define DS 1024
#define MATD ((size_t)DS * DS * sizeof(double))
#define PA 66

typedef double v4d __attribute__((ext_vector_type(4)));

__device__ inline double Qel(int i, int j) {
    if (i == j + 1) return sqrt((double)i) * 0.70710678118654752440;
    if (j == i + 1) return sqrt((double)j) * 0.70710678118654752440;
    return 0.0;
}

__device__ inline void fill_H(double* Hs, int tid) {
    const double CM2EV = 0.00012398419;
    const double E_S1 = 3.995, E_S2 = 4.9183;
    const double om6a = 596.0 * CM2EV, om10a = 919.0 * CM2EV;
    const double kapA = -0.0964, kapB = 0.1193, lam = 0.1825, gam = -0.018;
    for (int h = tid; h < 1024; h += 256) {
        int r = h >> 5, c = h & 31;
        int e = r >> 4, v6 = (r >> 2) & 3, v10 = r & 3;
        int e2 = c >> 4, w6 = (c >> 2) & 3, w10 = c & 3;
        double val = 0.0;
        if (r == c) val += (e ? E_S2 : E_S1) + om6a * v6 + om10a * v10;
        if (e == e2 && v10 == w10) val += (e ? kapB : kapA) * Qel(v6, w6);
        if (e != e2 && v6 == w6) {
            double q2 = 0.0;
            #pragma unroll
            for (int m = 0; m < 4; ++m) q2 += Qel(v10, m) * Qel(m, w10);
            val += lam * Qel(v10, w10) + gam * q2;
        }
        Hs[h] = val;
    }
}

// ------------------------------------------------ build G14 (+ Y/Z init) ----
// Blocks < 4096: G = I + (tau/8/14)*T (the k=14 Horner step applied to I).
// Blocks >= 4096: init Y (256 rows) and Z.
__global__ __launch_bounds__(256)
void build_G14(const float* __restrict__ logg, double* __restrict__ X,
               double* __restrict__ Y, double* __restrict__ Z)
{
    int tid = threadIdx.x;
    if (blockIdx.x >= 4096) {
        int idx = (blockIdx.x - 4096) * 256 + tid;
        if (idx < 256 * 1024) {
            int r = idx >> 10, i = idx & 1023;
            double v = 0.0;
            if (r < 2 && i % 33 == 0) {
                int a = i / 33;
                if ((a < 16) == (r == 0)) v = 1.0;
            }
            Y[idx] = v;
        } else if (idx < 256 * 1024 + 1024) {
            int i = idx - 256 * 1024;
            Z[i] = (i == 528) ? 1.0 : 0.0;
        }
        return;
    }
    __shared__ double Hs[1024];
    fill_H(Hs, tid);
    __syncthreads();
    double g = exp((double)logg[0]);
    const double sc = ((1.0 / 0.6582119569) / 8.0) / 14.0;
    int idx = blockIdx.x * 256 + tid;
    int r = idx >> 10, c = idx & 1023;
    int i = r >> 5, j = r & 31;
    int k = c >> 5, l = c & 31;
    double t = 0.0;
    if (k <= l) {
        if (i <= j) {
            if (i < 16 && j < 16) {
                int p = i + 16, q = j + 16;
                if ((p == k && q == l) || (p == l && q == k)) t += g;
            }
            if (i == k && j == l) t -= 0.5 * g * ((i >= 16) + (j >= 16));
        } else {
            if (j == l) t += Hs[i * 32 + k];
            if (k != l && j == k) t += Hs[i * 32 + l];
            if (i == k) t -= Hs[l * 32 + j];
            if (k != l && i == l) t -= Hs[k * 32 + j];
        }
    } else {
        if (i <= j) {
            double ha = 0.0;
            if (j == l) ha += Hs[i * 32 + k];
            if (j == k) ha -= Hs[i * 32 + l];
            if (i == k) ha -= Hs[l * 32 + j];
            if (i == l) ha += Hs[k * 32 + j];
            t -= ha;
        } else {
            if (i < 16 && j < 16 && (i + 16 == k) && (j + 16 == l)) t += g;
            if (i == k && j == l) t -= 0.5 * g * ((i >= 16) + (j >= 16));
        }
    }
    X[idx] = t * sc + ((r == c) ? 1.0 : 0.0);
}

// --------------------------------------------------------- sparse T-apply ---
// O = I + sck * (T @ M). XCD chunk-swizzle: consecutive dispatch (-> XCD
// round-robin) maps to contiguous 128-row chunks so each row's consumers
// share one XCD's L2.
__global__ __launch_bounds__(256)
void apply_T(const float* __restrict__ logg, const double* __restrict__ M,
             double* __restrict__ O, double invk)
{
    __shared__ double Hs[1024];
    const int tid = threadIdx.x;
    fill_H(Hs, tid);
    __syncthreads();
    const double g = exp((double)logg[0]);
    const double sck = ((1.0 / 0.6582119569) / 8.0) * invk;
    const int p = ((blockIdx.x & 7) << 7) | (blockIdx.x >> 3);   // XCD chunk
    const int i = p >> 5, j = p & 31;

    double a0 = 0.0, a1 = 0.0, a2 = 0.0, a3 = 0.0;
    const int e = tid;

#define ADDROW(q, wgt) { const double* r_ = M + (size_t)(q) * DS; double w_ = (wgt); \
    a0 += w_ * r_[e]; a1 += w_ * r_[e + 256];                                        \
    a2 += w_ * r_[e + 512]; a3 += w_ * r_[e + 768]; }

    if (i <= j) {
        for (int m = 0; m < 32; ++m) {
            double c = Hs[i * 32 + m];
            if (c != 0.0 && m != j) {
                if (m > j) ADDROW(m * 32 + j, -c)
                else       ADDROW(j * 32 + m,  c)
            }
        }
        for (int m = 0; m < 32; ++m) {
            double c = Hs[m * 32 + j];
            if (c != 0.0 && m != i) {
                if (i > m) ADDROW(i * 32 + m,  c)
                else       ADDROW(m * 32 + i, -c)
            }
        }
        if (i < 16 && j < 16) ADDROW((i + 16) * 32 + (j + 16), g)
        if (i >= 16 || j >= 16)
            ADDROW(p, -0.5 * g * (double)((i >= 16) + (j >= 16)))
    } else {
        for (int m = 0; m < 32; ++m) {
            double c = Hs[i * 32 + m];
            if (c != 0.0) {
                int lo = m < j ? m : j, hi = m < j ? j : m;
                ADDROW(lo * 32 + hi, c)
            }
        }
        for (int m = 0; m < 32; ++m) {
            double c = Hs[m * 32 + j];
            if (c != 0.0) {
                int lo = m < i ? m : i, hi = m < i ? i : m;
                ADDROW(lo * 32 + hi, -c)
            }
        }
        if (i < 16 && j < 16) ADDROW((i + 16) * 32 + (j + 16), g)
        ADDROW(p, -0.5 * g * (double)((i >= 16) + (j >= 16)))
    }
#undef ADDROW

    size_t base = (size_t)p * DS;
    O[base + e]       = sck * a0 + ((p == e)       ? 1.0 : 0.0);
    O[base + e + 256] = sck * a1 + ((p == e + 256) ? 1.0 : 0.0);
    O[base + e + 512] = sck * a2 + ((p == e + 512) ? 1.0 : 0.0);
    O[base + e + 768] = sck * a3 + ((p == e + 768) ? 1.0 : 0.0);
}

// --------------------------------------------------------- dgemm (MFMA f64) -
// ROUND-9 VERBATIM (FROZEN). D = A*B. 64x64 tile, 1024 threads (16 waves):
// 4 output quadrants x 4 k-groups (k-split-4 within KT=64); 3-phase reduction.
__global__ __launch_bounds__(1024, 1)
void dgemm(const double* __restrict__ A, const double* __restrict__ B,
           double* __restrict__ D)
{
    __shared__ double As[64 * PA];
    __shared__ double Bs[64 * PA];
    const int tid = threadIdx.x;
    const int bm = blockIdx.x << 6, bn = blockIdx.y << 6;
    const int w = tid >> 6, lane = tid & 63;
    const int lr = lane & 15, lk = lane >> 4;
    const int p = w & 3, kg = w >> 2;
    const int wr = (p >> 1) << 5, wc = (p & 1) << 5;

    v4d acc[2][2];
    #pragma unroll
    for (int si = 0; si < 2; ++si)
        #pragma unroll
        for (int sj = 0; sj < 2; ++sj) acc[si][sj] = (v4d){0., 0., 0., 0.};

    const int ra = tid >> 4;
    const int cs = (tid & 15) << 2;
    const double* gA = A + (size_t)(bm + ra) * DS + cs;
    const double* gB = B + (size_t)ra * DS + bn + cs;
    double va[4], vb[4];
    #pragma unroll
    for (int u = 0; u < 4; ++u) { va[u] = gA[u]; vb[u] = gB[u]; }

    for (int kt = 0; kt < DS; kt += 64) {
        #pragma unroll
        for (int u = 0; u < 4; ++u) {
            As[ra * PA + cs + u] = va[u];
            Bs[ra * PA + cs + u] = vb[u];
        }
        __syncthreads();
        if (kt + 64 < DS) {
            #pragma unroll
            for (int u = 0; u < 4; ++u) {
                va[u] = gA[kt + 64 + u];
                vb[u] = gB[(size_t)(kt + 64) * DS + u];
            }
        }
        #pragma unroll
        for (int s = 0; s < 4; ++s) {
            int k = (kg << 4) + (s << 2) + lk;
            double a0 = As[(wr + lr) * PA + k];
            double a1 = As[(wr + 16 + lr) * PA + k];
            double b0 = Bs[k * PA + wc + lr];
            double b1 = Bs[k * PA + wc + 16 + lr];
            acc[0][0] = __builtin_amdgcn_mfma_f64_16x16x4f64(a0, b0, acc[0][0], 0, 0, 0);
            acc[0][1] = __builtin_amdgcn_mfma_f64_16x16x4f64(a0, b1, acc[0][1], 0, 0, 0);
            acc[1][0] = __builtin_amdgcn_mfma_f64_16x16x4f64(a1, b0, acc[1][0], 0, 0, 0);
            acc[1][1] = __builtin_amdgcn_mfma_f64_16x16x4f64(a1, b1, acc[1][1], 0, 0, 0);
        }
        __syncthreads();
    }

    double* red = As;
    if (kg == 3) {
        #pragma unroll
        for (int si = 0; si < 2; ++si)
            #pragma unroll
            for (int sj = 0; sj < 2; ++sj)
                #pragma unroll
                for (int r = 0; r < 4; ++r)
                    red[(wr + si * 16 + lk + 4 * r) * 64 + wc + sj * 16 + lr]
                        = acc[si][sj][r];
    }
    __syncthreads();
    if (kg == 2) {
        #pragma unroll
        for (int si = 0; si < 2; ++si)
            #pragma unroll
            for (int sj = 0; sj < 2; ++sj)
                #pragma unroll
                for (int r = 0; r < 4; ++r)
                    red[(wr + si * 16 + lk + 4 * r) * 64 + wc + sj * 16 + lr]
                        += acc[si][sj][r];
    }
    __syncthreads();
    if (kg == 1) {
        #pragma unroll
        for (int si = 0; si < 2; ++si)
            #pragma unroll
            for (int sj = 0; sj < 2; ++sj)
                #pragma unroll
                for (int r = 0; r < 4; ++r)
                    red[(wr + si * 16 + lk + 4 * r) * 64 + wc + sj * 16 + lr]
                        += acc[si][sj][r];
    }
    __syncthreads();
    if (kg == 0) {
        #pragma unroll
        for (int si = 0; si < 2; ++si)
            #pragma unroll
            for (int sj = 0; sj < 2; ++sj) {
                int col = bn + wc + sj * 16 + lr;
                #pragma unroll
                for (int r = 0; r < 4; ++r) {
                    int row = bm + wr + si * 16 + lk + 4 * r;
                    D[(size_t)row * DS + col] = acc[si][sj][r]
                        + red[(wr + si * 16 + lk + 4 * r) * 64 + wc + sj * 16 + lr];
                }
            }
    }
}

// --------------------------------------------------------- ypart ------------
__global__ __launch_bounds__(256)
void ypart(const double* __restrict__ P, const double* __restrict__ Y,
           double* __restrict__ scratch, int SR)
{
    __shared__ double Yld[32 * 64];
    __shared__ double red[32 * 64];
    const int tid = threadIdx.x;
    const int cc = tid & 63, kw = tid >> 6;
    const int col = (blockIdx.x << 6) + cc;
    const int kb = blockIdx.y << 6;
    const int r0 = blockIdx.z << 5;

    for (int idx = tid; idx < 32 * 64; idx += 256) {
        int r = idx >> 6, kk = idx & 63;
        Yld[idx] = Y[(size_t)(r0 + r) * DS + kb + kk];
    }
    __syncthreads();

    double acc[32];
    #pragma unroll
    for (int r = 0; r < 32; ++r) acc[r] = 0.0;

    #pragma unroll
    for (int kk = 0; kk < 16; ++kk) {
        int kl = (kw << 4) + kk;
        double pv = P[(size_t)(kb + kl) * DS + col];
        #pragma unroll
        for (int r = 0; r < 32; ++r)
            acc[r] += Yld[(r << 6) + kl] * pv;
    }

    __syncthreads();
    if (kw == 3) {
        #pragma unroll
        for (int r = 0; r < 32; ++r) red[(r << 6) + cc] = acc[r];
    }
    __syncthreads();
    if (kw == 2) {
        #pragma unroll
        for (int r = 0; r < 32; ++r) red[(r << 6) + cc] += acc[r];
    }
    __syncthreads();
    if (kw == 1) {
        #pragma unroll
        for (int r = 0; r < 32; ++r) red[(r << 6) + cc] += acc[r];
    }
    __syncthreads();
    if (kw == 0) {
        #pragma unroll
        for (int r = 0; r < 32; ++r) red[(r << 6) + cc] += acc[r];
    }
    __syncthreads();
    for (int idx = tid; idx < 32 * 64; idx += 256) {
        int r = idx >> 6, c2 = idx & 63;
        scratch[((size_t)blockIdx.y * SR + r0 + r) * DS + (blockIdx.x << 6) + c2]
            = red[idx];
    }
}

// --------------------------------------------------------- yreduce ----------
__global__ __launch_bounds__(256)
void yreduce(const double* __restrict__ scratch, double* __restrict__ Y,
             int M, int SR)
{
    int idx = blockIdx.x * 256 + threadIdx.x;
    int r = idx >> 10, c = idx & 1023;
    double s = 0.0;
    #pragma unroll
    for (int q = 0; q < 16; ++q)
        s += scratch[((size_t)q * SR + r) * DS + c];
    Y[(size_t)(M + r) * DS + c] = s;
}

// --------------------------------------------------------- Z matvec ---------
__global__ __launch_bounds__(256)
void zstep(const double* __restrict__ V, const double* __restrict__ Zin,
           double* __restrict__ Zout)
{
    int row = blockIdx.x * 4 + (threadIdx.x >> 6);
    int lane = threadIdx.x & 63;
    const double2* r_ = (const double2*)(V + (size_t)row * DS);
    const double2* z_ = (const double2*)Zin;
    double s = 0.0;
    #pragma unroll
    for (int k = 0; k < 8; ++k) {
        double2 a = r_[(k << 6) + lane];
        double2 b = z_[(k << 6) + lane];
        s += a.x * b.x + a.y * b.y;
    }
    #pragma unroll
    for (int off = 32; off; off >>= 1) s += __shfl_down(s, off);
    if (lane == 0) Zout[row] = s;
}

// --------------------------------------------------------- output -----------
// t = a + 128 j; y = Y row (2a+k); z = Z[j].
__global__ __launch_bounds__(128)
void final_pops(const double* __restrict__ Y, const double* __restrict__ Z,
                float* __restrict__ out, int n)
{
    int t = blockIdx.x;
    int k = threadIdx.x >> 6, lane = threadIdx.x & 63;
    int a = t & 127, j = t >> 7;
    const double* y = Y + (size_t)(2 * a + k) * 1024;
    const double* z = Z + (size_t)j * 1024;
    double s = 0.0;
    for (int i = lane; i < 1024; i += 64) s += y[i] * z[i];
    #pragma unroll
    for (int off = 32; off; off >>= 1) s += __shfl_down(s, off);
    if (lane == 0) {
        out[(size_t)(k + 1) * n + t] = (float)s;
        if (k == 0) out[t] = 0.0f;
    }
}

// --------------------------------------------------------- host -------------
static inline void ydouble2(const double* P, double* Y, double* scr, int M,
                            hipStream_t stream)
{
    int gz = (M + 31) / 32; if (gz < 1) gz = 1;
    int SR = gz * 32;
    ypart<<<dim3(16, 16, gz), 256, 0, stream>>>(P, Y, scr, SR);
    yreduce<<<SR * 4, 256, 0, stream>>>(scr, Y, M, SR);
}

extern "C" void kernel_launch(void* const* d_in, const int* in_sizes, int n_in,
                              void* d_out, int out_size, void* d_ws, size_t ws_size,
                              hipStream_t stream)
{
    const float* logg = (const float*)d_in[0];
    float* out = (float*)d_out;
    const int n = out_size / 3;
    (void)in_sizes; (void)n_in; (void)ws_size;

    char* ws = (char*)d_ws;
    double* b0 = (double*)(ws + 0 * MATD);
    double* b1 = (double*)(ws + 1 * MATD);
    double* b2 = (double*)(ws + 2 * MATD);
    double* scr = (double*)(ws + 3 * MATD);  // up to 16 x 128 x 1024 (16 MB)
    double* Y  = (double*)(ws + 5 * MATD);   // 256 rows x 1024 (2 MB)
    double* Z  = Y + 256 * 1024;             // 8 x 1024

    dim3 g2(16, 16);

    // ---- W = Taylor14(tau*T/8): G14 dense (+Y/Z init), 13 sparse applies ---
    build_G14<<<4096 + 1028, 256, 0, stream>>>(logg, b0, Y, Z);
    double* src = b0; double* dst = b1;
    for (int k = 13; k >= 1; --k) {
        apply_T<<<1024, 256, 0, stream>>>(logg, src, dst, 1.0 / (double)k);
        double* t = src; src = dst; dst = t;
    }
    // 13 applies (odd) -> W in b1

    // ---- squarings interleaved with Y-doubling ----
    dgemm<<<g2, 1024, 0, stream>>>(b1, b1, b0);   // W^2
    dgemm<<<g2, 1024, 0, stream>>>(b0, b0, b2);   // W^4
    dgemm<<<g2, 1024, 0, stream>>>(b2, b2, b0);   // U = W^8
    ydouble2(b0, Y, scr, 2, stream);              // a += 1   (U)
    dgemm<<<g2, 1024, 0, stream>>>(b0, b0, b1);   // U^2
    ydouble2(b1, Y, scr, 4, stream);              // a += 2
    dgemm<<<g2, 1024, 0, stream>>>(b1, b1, b2);   // U^4
    ydouble2(b2, Y, scr, 8, stream);              // a += 4
    dgemm<<<g2, 1024, 0, stream>>>(b2, b2, b1);   // U^8
    ydouble2(b1, Y, scr, 16, stream);             // a += 8
    dgemm<<<g2, 1024, 0, stream>>>(b1, b1, b2);   // U^16
    ydouble2(b2, Y, scr, 32, stream);             // a += 16
    dgemm<<<g2, 1024, 0, stream>>>(b2, b2, b1);   // U^32
    ydouble2(b1, Y, scr, 64, stream);             // a += 32
    dgemm<<<g2, 1024, 0, stream>>>(b1, b1, b2);   // U^64
    ydouble2(b2, Y, scr, 128, stream);            // a += 64
    dgemm<<<g2, 1024, 0, stream>>>(b2, b2, b1);   // U^128

    // ---- Z chain: z_j = (U^128)^j x0, j = 1..7 ----
    for (int j = 1; j < 8; ++j)
        zstep<<<256, 256, 0, stream>>>(b1, Z + (size_t)(j - 1) * 1024,
                                       Z + (size_t)j * 1024);

    final_pops<<<n, 128, 0, stream>>>(Y, Z, out, n);
}